// Round 4
// baseline (5074.606 us; speedup 1.0000x reference)
//
#include <hip/hip_runtime.h>
#include <math.h>

#define NP 2048           // points per batch (n == m)
#define DF 256            // feature dim
#define NPROB 8           // 2 OTs * 4 batches
#define NTOT 8192         // total rows per feature tensor

constexpr float F_MU  = 1.0f / 2048.0f;   // uniform marginal 1/n
constexpr float SQ    = 65535.0f;         // K u16 quantization scale
constexpr float EPS_U = 65535.0f * 1e-8f; // stab for u-update (scale-consistent)
constexpr float EPS_V = 1e-8f;            // stab for v-update (unscaled)

typedef _Float16 f16x8 __attribute__((ext_vector_type(8)));
typedef float    f32x4 __attribute__((ext_vector_type(4)));

// workspace layout (float units)
constexpr size_t OFF_K   = 0;                            // ushort[8*2048*2048]
constexpr size_t SZ_Kf   = (size_t)NPROB * NP * NP / 2;  // 16,777,216 floats
constexpr size_t OFF_VA  = OFF_K + SZ_Kf;                // 3 ping-pong-pong buffers
constexpr size_t SZ_VA   = (size_t)3 * NPROB * NP;
constexpr size_t OFF_U   = OFF_VA + SZ_VA;
constexpr size_t SZ_U    = (size_t)NPROB * NP;
constexpr size_t OFF_INV = OFF_U + SZ_U;
constexpr size_t SZ_INV  = (size_t)3 * NTOT;
constexpr size_t OFF_SUM = OFF_INV + SZ_INV;

__device__ inline float4 unpack4(unsigned a, unsigned b) {
    return make_float4((float)(a & 0xffffu), (float)(a >> 16),
                       (float)(b & 0xffffu), (float)(b >> 16));
}

// ---------------------------------------------------------------- row norms
__global__ __launch_bounds__(256) void k_norms(const float* __restrict__ src,
                                               const float* __restrict__ tgt,
                                               const float* __restrict__ gen,
                                               float* __restrict__ inv) {
    int gw   = (blockIdx.x * 256 + threadIdx.x) >> 6;   // 0 .. 3*8192-1
    int lane = threadIdx.x & 63;
    int a = gw >> 13;
    int r = gw & 8191;
    const float* base = (a == 0 ? src : (a == 1 ? tgt : gen)) + (size_t)r * DF;
    float4 x = reinterpret_cast<const float4*>(base)[lane];
    float s = x.x * x.x + x.y * x.y + x.z * x.z + x.w * x.w;
    #pragma unroll
    for (int off = 32; off; off >>= 1) s += __shfl_xor(s, off);
    if (lane == 0) inv[gw] = 1.0f / (sqrtf(s) + 1e-8f);
}

// ---------------------------------------------------------------- zero init
__global__ void k_init(float* __restrict__ va0, float* __restrict__ sum) {
    int i = blockIdx.x * 256 + threadIdx.x;
    if (i < NPROB * NP) va0[i] = 0.0f;
    if (i == 0) sum[0] = 0.0f;
}

// ---------------------------------------------------------------- K build via f16 MFMA
// 128x128 tile per block, 4 waves in 2x2, each wave 64x64 via 4x4 fragments of
// mfma_f32_16x16x32_f16. BK=128 K-panel staged in LDS (f16, XOR granule
// swizzle g^=(row&7) -> 2-way-free b128 reads). Epilogue: exp + u16 quantize.
#define BK 128
__global__ __launch_bounds__(256) void k_build(const float* __restrict__ src,
                                               const float* __restrict__ tgt,
                                               const float* __restrict__ gen,
                                               const float* __restrict__ inv,
                                               unsigned short* __restrict__ K) {
    __shared__ _Float16 As[128 * BK];   // 32 KB, row stride 128 halfs = 16 granules
    __shared__ _Float16 Bs[128 * BK];   // 32 KB
    int bid = blockIdx.x;          // 2048 = 8 problems * 16 * 16 tiles
    int p   = bid >> 8;
    int t   = bid & 255;
    int ti  = t >> 4, tj = t & 15;
    int ot  = p >> 2, b = p & 3;
    const float* X    = (ot == 0) ? src : tgt;
    const float* Y    = (ot == 0) ? tgt : gen;
    const float* invx = inv + (ot == 0 ? 0 : NTOT);
    const float* invy = inv + (ot == 0 ? NTOT : 2 * NTOT);
    int rowA0 = b * NP + ti * 128;
    int rowB0 = b * NP + tj * 128;

    int tid  = threadIdx.x;
    int w    = tid >> 6, lane = tid & 63;
    int wr   = w >> 1,  wc   = w & 1;
    int lr   = lane & 15, lk = lane >> 4;   // fragment row / k-group

    f32x4 acc[4][4];
    #pragma unroll
    for (int m = 0; m < 4; ++m)
        #pragma unroll
        for (int n = 0; n < 4; ++n) acc[m][n] = (f32x4){0.f, 0.f, 0.f, 0.f};

    for (int kb = 0; kb < DF; kb += BK) {
        __syncthreads();
        // stage 128 rows x 128 cols f16 for both matrices; 2048 granules each
        #pragma unroll
        for (int s = 0; s < 8; ++s) {
            int idx = tid + s * 256;      // 0..2047
            int row = idx >> 4;           // 16 granules (16B) per row
            int g   = idx & 15;
            int gs  = g ^ (row & 7);      // XOR swizzle
            const float4* xp = reinterpret_cast<const float4*>(
                X + (size_t)(rowA0 + row) * DF + kb + g * 8);
            float4 x0 = xp[0], x1 = xp[1];
            float  sa = invx[rowA0 + row];
            f16x8 hv;
            hv[0] = (_Float16)(x0.x * sa); hv[1] = (_Float16)(x0.y * sa);
            hv[2] = (_Float16)(x0.z * sa); hv[3] = (_Float16)(x0.w * sa);
            hv[4] = (_Float16)(x1.x * sa); hv[5] = (_Float16)(x1.y * sa);
            hv[6] = (_Float16)(x1.z * sa); hv[7] = (_Float16)(x1.w * sa);
            *reinterpret_cast<f16x8*>(&As[row * BK + gs * 8]) = hv;
            const float4* yp = reinterpret_cast<const float4*>(
                Y + (size_t)(rowB0 + row) * DF + kb + g * 8);
            float4 y0 = yp[0], y1 = yp[1];
            float  sb = invy[rowB0 + row];
            f16x8 hw;
            hw[0] = (_Float16)(y0.x * sb); hw[1] = (_Float16)(y0.y * sb);
            hw[2] = (_Float16)(y0.z * sb); hw[3] = (_Float16)(y0.w * sb);
            hw[4] = (_Float16)(y1.x * sb); hw[5] = (_Float16)(y1.y * sb);
            hw[6] = (_Float16)(y1.z * sb); hw[7] = (_Float16)(y1.w * sb);
            *reinterpret_cast<f16x8*>(&Bs[row * BK + gs * 8]) = hw;
        }
        __syncthreads();
        #pragma unroll
        for (int ks = 0; ks < BK / 32; ++ks) {
            int kg = ks * 4 + lk;         // granule within row for this lane
            f16x8 af[4], bf[4];
            #pragma unroll
            for (int m = 0; m < 4; ++m) {
                int row = wr * 64 + m * 16 + lr;
                af[m] = *reinterpret_cast<const f16x8*>(&As[row * BK + (kg ^ (row & 7)) * 8]);
            }
            #pragma unroll
            for (int n = 0; n < 4; ++n) {
                int row = wc * 64 + n * 16 + lr;
                bf[n] = *reinterpret_cast<const f16x8*>(&Bs[row * BK + (kg ^ (row & 7)) * 8]);
            }
            #pragma unroll
            for (int m = 0; m < 4; ++m)
                #pragma unroll
                for (int n = 0; n < 4; ++n)
                    acc[m][n] = __builtin_amdgcn_mfma_f32_16x16x32_f16(af[m], bf[n], acc[m][n], 0, 0, 0);
        }
    }

    // epilogue: C/D layout col = lane&15, row = (lane>>4)*4 + reg
    unsigned short* Kp = K + (size_t)p * NP * NP;
    #pragma unroll
    for (int m = 0; m < 4; ++m) {
        #pragma unroll
        for (int r4 = 0; r4 < 4; ++r4) {
            int gi = ti * 128 + wr * 64 + m * 16 + lk * 4 + r4;
            #pragma unroll
            for (int n = 0; n < 4; ++n) {
                int gj = tj * 128 + wc * 64 + n * 16 + lr;
                float kv = __expf(acc[m][n][r4] - 1.0f);
                Kp[(size_t)gi * NP + gj] =
                    (unsigned short)__float2uint_rn(fminf(kv * SQ, 65535.0f));
            }
        }
    }
}

// ---------------------------------------------------------------- one Sinkhorn iteration
// 1024 blocks (8 problems * 128), 16 rows each. Phase A: stream the 16-row
// u16 K-tile into LDS via global_load_lds width=16 (pure streaming, max MLP,
// no VGPR roundtrip). Phase B: dot/shfl/scale chains run out of LDS (low
// latency). Cross-wave combine reuses the tile LDS after a barrier.
#define TROWS 16
__global__ __launch_bounds__(256) void k_sink(const unsigned short* __restrict__ K,
                                              float* __restrict__ u,
                                              const float* __restrict__ vR,
                                              float* __restrict__ vW,
                                              float* __restrict__ vZ,
                                              int first) {
    __shared__ __align__(16) unsigned short tile[TROWS * NP];   // 64 KB
    int bid = blockIdx.x;        // 1024 = 8 problems * 128 blocks
    int p   = bid >> 7;
    int blk = bid & 127;
    int tid = threadIdx.x;
    int w   = tid >> 6, lane = tid & 63;

    // zero the Z buffer slice (16384 floats / 1024 blocks = 16 each)
    if (tid < 16) vZ[bid * 16 + tid] = 0.0f;

    const unsigned short* Kp = K + (size_t)p * NP * NP;
    int row0 = blk * TROWS;

    // ---- Phase A: stage 16 rows (4 per wave) into LDS, 16 issues/wave
    #pragma unroll
    for (int r = 0; r < 4; ++r) {
        int row = w * 4 + r;
        const unsigned short* g = Kp + (size_t)(row0 + row) * NP + lane * 8;
        #pragma unroll
        for (int j = 0; j < 4; ++j) {
            __builtin_amdgcn_global_load_lds(
                (const __attribute__((address_space(1))) unsigned int*)(const void*)(g + j * 512),
                (__attribute__((address_space(3))) unsigned int*)(void*)&tile[row * NP + j * 512],
                16, 0, 0);
        }
    }

    // v for the 32 columns this lane owns: cols (j*64+lane)*8 + {0..7}
    float vr[32];
    if (first) {
        #pragma unroll
        for (int c = 0; c < 32; ++c) vr[c] = 1.0f;
    } else {
        const float4* vRp = reinterpret_cast<const float4*>(vR + (size_t)p * NP);
        #pragma unroll
        for (int j = 0; j < 4; ++j)
            #pragma unroll
            for (int h = 0; h < 2; ++h) {
                float4 r = vRp[j * 128 + lane * 2 + h];
                vr[j * 8 + h * 4 + 0] = F_MU / (r.x + EPS_V);
                vr[j * 8 + h * 4 + 1] = F_MU / (r.y + EPS_V);
                vr[j * 8 + h * 4 + 2] = F_MU / (r.z + EPS_V);
                vr[j * 8 + h * 4 + 3] = F_MU / (r.w + EPS_V);
            }
    }

    float va[32];
    #pragma unroll
    for (int c = 0; c < 32; ++c) va[c] = 0.0f;

    __syncthreads();   // drains vmcnt (global_load_lds) + all waves staged

    // ---- Phase B: per wave, its own 4 rows out of LDS
    #pragma unroll
    for (int r = 0; r < 4; ++r) {
        int row = w * 4 + r;
        const uint4* kr = reinterpret_cast<const uint4*>(&tile[row * NP]);
        uint4 q[4];
        #pragma unroll
        for (int j = 0; j < 4; ++j) q[j] = kr[j * 64 + lane];
        float d = 0.0f;
        #pragma unroll
        for (int j = 0; j < 4; ++j) {
            float4 f01 = unpack4(q[j].x, q[j].y);
            float4 f23 = unpack4(q[j].z, q[j].w);
            d += f01.x * vr[j*8+0] + f01.y * vr[j*8+1] + f01.z * vr[j*8+2] + f01.w * vr[j*8+3]
               + f23.x * vr[j*8+4] + f23.y * vr[j*8+5] + f23.z * vr[j*8+6] + f23.w * vr[j*8+7];
        }
        #pragma unroll
        for (int off = 32; off; off >>= 1) d += __shfl_xor(d, off);
        float ui = F_MU / (d + EPS_U);
        if (lane == 0) u[(size_t)p * NP + row0 + row] = ui;
        #pragma unroll
        for (int j = 0; j < 4; ++j) {
            float4 f01 = unpack4(q[j].x, q[j].y);
            float4 f23 = unpack4(q[j].z, q[j].w);
            va[j*8+0] += f01.x * ui; va[j*8+1] += f01.y * ui;
            va[j*8+2] += f01.z * ui; va[j*8+3] += f01.w * ui;
            va[j*8+4] += f23.x * ui; va[j*8+5] += f23.y * ui;
            va[j*8+6] += f23.z * ui; va[j*8+7] += f23.w * ui;
        }
    }

    // ---- cross-wave combine: reuse tile LDS as float4[4][512] (32 KB)
    __syncthreads();   // all waves done reading tile
    float4* cw = reinterpret_cast<float4*>(tile);
    #pragma unroll
    for (int j = 0; j < 4; ++j)
        #pragma unroll
        for (int h = 0; h < 2; ++h)
            cw[w * 512 + (j * 2 + h) * 64 + lane] =
                make_float4(va[j*8+h*4+0], va[j*8+h*4+1], va[j*8+h*4+2], va[j*8+h*4+3]);
    __syncthreads();
    float* vWp = vW + (size_t)p * NP;
    #pragma unroll
    for (int s = 0; s < 2; ++s) {
        int pi = tid + s * 256;               // physical float4 index 0..511
        int lr = pi & 63, hr = (pi >> 6) & 1, jr = pi >> 7;
        int col4 = jr * 128 + lr * 2 + hr;    // logical col/4
        float4 a0 = cw[pi], a1 = cw[512 + pi], a2 = cw[1024 + pi], a3 = cw[1536 + pi];
        atomicAdd(&vWp[4 * col4 + 0], a0.x + a1.x + a2.x + a3.x);
        atomicAdd(&vWp[4 * col4 + 1], a0.y + a1.y + a2.y + a3.y);
        atomicAdd(&vWp[4 * col4 + 2], a0.z + a1.z + a2.z + a3.z);
        atomicAdd(&vWp[4 * col4 + 3], a0.w + a1.w + a2.w + a3.w);
    }
}

// ---------------------------------------------------------------- mean |f1-f2|
// v1/v2 staged in LDS (not 64 regs/lane) to keep VGPRs low.
__global__ __launch_bounds__(256) void k_freduce(const unsigned short* __restrict__ K,
                                                 const float* __restrict__ u,
                                                 const float* __restrict__ vF,
                                                 float* __restrict__ sum) {
    __shared__ float vsh[2][NP];   // 16 KB
    int bid = blockIdx.x;        // 512 = 4 batches * 128 blocks
    int b   = bid >> 7;
    int blk = bid & 127;
    int tid = threadIdx.x;
    int w   = tid >> 6, lane = tid & 63;
    int p1 = b, p2 = 4 + b;

    #pragma unroll
    for (int s = 0; s < 8; ++s) {
        int i = tid + s * 256;
        vsh[0][i] = F_MU / (vF[(size_t)p1 * NP + i] + EPS_V);
        vsh[1][i] = F_MU / (vF[(size_t)p2 * NP + i] + EPS_V);
    }
    __syncthreads();

    const unsigned short* K1 = K + (size_t)p1 * NP * NP;
    const unsigned short* K2 = K + (size_t)p2 * NP * NP;
    float acc = 0.0f;
    int row0 = blk * 16 + w * 4;
    for (int r = 0; r < 4; ++r) {
        int row = row0 + r;
        float u1 = u[(size_t)p1 * NP + row], u2 = u[(size_t)p2 * NP + row];
        const uint4* kr1 = reinterpret_cast<const uint4*>(K1 + (size_t)row * NP);
        const uint4* kr2 = reinterpret_cast<const uint4*>(K2 + (size_t)row * NP);
        #pragma unroll
        for (int j = 0; j < 4; ++j) {
            uint4 q1 = kr1[j * 64 + lane];
            uint4 q2 = kr2[j * 64 + lane];
            int cb = (j * 64 + lane) * 8;
            float4 v1a = *reinterpret_cast<const float4*>(&vsh[0][cb]);
            float4 v1b = *reinterpret_cast<const float4*>(&vsh[0][cb + 4]);
            float4 v2a = *reinterpret_cast<const float4*>(&vsh[1][cb]);
            float4 v2b = *reinterpret_cast<const float4*>(&vsh[1][cb + 4]);
            float4 a01 = unpack4(q1.x, q1.y), a23 = unpack4(q1.z, q1.w);
            float4 b01 = unpack4(q2.x, q2.y), b23 = unpack4(q2.z, q2.w);
            acc += fabsf(u1 * a01.x * v1a.x - u2 * b01.x * v2a.x);
            acc += fabsf(u1 * a01.y * v1a.y - u2 * b01.y * v2a.y);
            acc += fabsf(u1 * a01.z * v1a.z - u2 * b01.z * v2a.z);
            acc += fabsf(u1 * a01.w * v1a.w - u2 * b01.w * v2a.w);
            acc += fabsf(u1 * a23.x * v1b.x - u2 * b23.x * v2b.x);
            acc += fabsf(u1 * a23.y * v1b.y - u2 * b23.y * v2b.y);
            acc += fabsf(u1 * a23.z * v1b.z - u2 * b23.z * v2b.z);
            acc += fabsf(u1 * a23.w * v1b.w - u2 * b23.w * v2b.w);
        }
    }
    #pragma unroll
    for (int off = 32; off; off >>= 1) acc += __shfl_xor(acc, off);
    __shared__ float red[4];
    if (lane == 0) red[w] = acc;
    __syncthreads();
    if (tid == 0) atomicAdd(sum, red[0] + red[1] + red[2] + red[3]);
}

__global__ void k_final(const float* __restrict__ sum, float* __restrict__ out) {
    out[0] = sum[0] * (1.0f / 16777216.0f);   // / (4*2048*2048)
}

// ---------------------------------------------------------------- launch
extern "C" void kernel_launch(void* const* d_in, const int* in_sizes, int n_in,
                              void* d_out, int out_size, void* d_ws, size_t ws_size,
                              hipStream_t stream) {
    const float* src = (const float*)d_in[0];
    const float* tgt = (const float*)d_in[1];
    const float* gen = (const float*)d_in[2];
    float* ws  = (float*)d_ws;
    unsigned short* Kq = (unsigned short*)(ws + OFF_K);
    float* va  = ws + OFF_VA;
    float* uu  = ws + OFF_U;
    float* inv = ws + OFF_INV;
    float* sum = ws + OFF_SUM;
    float* out = (float*)d_out;

    hipLaunchKernelGGL(k_norms, dim3(6144), dim3(256), 0, stream, src, tgt, gen, inv);
    hipLaunchKernelGGL(k_init,  dim3(65),   dim3(256), 0, stream, va, sum);
    hipLaunchKernelGGL(k_build, dim3(2048), dim3(256), 0, stream, src, tgt, gen, inv, Kq);
    for (int t = 0; t < 50; ++t) {
        float* R = va + ((size_t)((t + 2) % 3)) * (NPROB * NP);  // read (iter t-1 result)
        float* W = va + ((size_t)(t % 3))       * (NPROB * NP);  // accumulate
        float* Z = va + ((size_t)((t + 1) % 3)) * (NPROB * NP);  // zero for iter t+1
        hipLaunchKernelGGL(k_sink, dim3(1024), dim3(256), 0, stream,
                           Kq, uu, R, W, Z, (t == 0) ? 1 : 0);
    }
    // final v is in buffer (49 % 3) == 1
    hipLaunchKernelGGL(k_freduce, dim3(512), dim3(256), 0, stream,
                       Kq, uu, va + (size_t)1 * (NPROB * NP), sum);
    hipLaunchKernelGGL(k_final, dim3(1), dim3(1), 0, stream, sum, out);
}

// Round 5
// 2884.705 us; speedup vs baseline: 1.7591x; 1.7591x over previous
//
#include <hip/hip_runtime.h>
#include <math.h>

#define NP 2048           // points per batch (n == m)
#define DF 256            // feature dim
#define NPROB 8           // 2 OTs * 4 batches
#define NTOT 8192         // total rows per feature tensor
#define NITER 50

constexpr float F_MU  = 1.0f / 2048.0f;   // uniform marginal 1/n
constexpr float SQ    = 255.0f;           // K u8 quantization scale
constexpr float EPS_U = 255.0f * 1e-8f;   // stab for u-update (scale-consistent)
constexpr float EPS_V = 1e-8f;            // stab for v-update (unscaled)

typedef _Float16 f16x8 __attribute__((ext_vector_type(8)));
typedef float    f32x4 __attribute__((ext_vector_type(4)));

// workspace layout (float units)
constexpr size_t OFF_K   = 0;                            // u8[8*2048*2048] = 33.5 MB
constexpr size_t SZ_Kf   = (size_t)NPROB * NP * NP / 4;  // 8,388,608 floats
constexpr size_t OFF_VA  = OFF_K + SZ_Kf;                // 3 ping-pong-pong buffers
constexpr size_t SZ_VA   = (size_t)3 * NPROB * NP;       // 49,152
constexpr size_t OFF_INV = OFF_VA + SZ_VA;
constexpr size_t SZ_INV  = (size_t)3 * NTOT;
constexpr size_t OFF_SUM = OFF_INV + SZ_INV;
constexpr size_t OFF_CNT = OFF_SUM + 1;                  // 4 uint barrier counters

__device__ inline float mac4(unsigned a, const float* v) {
    return (float)(a & 255u)         * v[0] + (float)((a >> 8) & 255u) * v[1]
         + (float)((a >> 16) & 255u) * v[2] + (float)(a >> 24)         * v[3];
}

__device__ inline float ad4(unsigned a, unsigned b, float u1, float u2,
                            const float* v1, const float* v2) {
    float s;
    s  = fabsf(u1 * (float)(a & 255u)          * v1[0] - u2 * (float)(b & 255u)          * v2[0]);
    s += fabsf(u1 * (float)((a >> 8)  & 255u)  * v1[1] - u2 * (float)((b >> 8)  & 255u)  * v2[1]);
    s += fabsf(u1 * (float)((a >> 16) & 255u)  * v1[2] - u2 * (float)((b >> 16) & 255u)  * v2[2]);
    s += fabsf(u1 * (float)(a >> 24)           * v1[3] - u2 * (float)(b >> 24)           * v2[3]);
    return s;
}

// ---------------------------------------------------------------- row norms
__global__ __launch_bounds__(256) void k_norms(const float* __restrict__ src,
                                               const float* __restrict__ tgt,
                                               const float* __restrict__ gen,
                                               float* __restrict__ inv) {
    int gw   = (blockIdx.x * 256 + threadIdx.x) >> 6;   // 0 .. 3*8192-1
    int lane = threadIdx.x & 63;
    int a = gw >> 13;
    int r = gw & 8191;
    const float* base = (a == 0 ? src : (a == 1 ? tgt : gen)) + (size_t)r * DF;
    float4 x = reinterpret_cast<const float4*>(base)[lane];
    float s = x.x * x.x + x.y * x.y + x.z * x.z + x.w * x.w;
    #pragma unroll
    for (int off = 32; off; off >>= 1) s += __shfl_xor(s, off);
    if (lane == 0) inv[gw] = 1.0f / (sqrtf(s) + 1e-8f);
}

// ---------------------------------------------------------------- zero init
__global__ void k_init(float* __restrict__ va0, float* __restrict__ sum,
                       unsigned int* __restrict__ cnt) {
    int i = blockIdx.x * 256 + threadIdx.x;
    if (i < NPROB * NP) va0[i] = 0.0f;
    if (i == 0) sum[0] = 0.0f;
    if (i < 4) cnt[i] = 0u;
}

// ---------------------------------------------------------------- K build via f16 MFMA
// 128x128 tile per block, 4 waves in 2x2, each wave 64x64 via 4x4 fragments of
// mfma_f32_16x16x32_f16. BK=128 K-panel staged in LDS (f16, XOR granule
// swizzle). Epilogue: exp + u8 quantize (scale 255).
#define BK 128
__global__ __launch_bounds__(256) void k_build(const float* __restrict__ src,
                                               const float* __restrict__ tgt,
                                               const float* __restrict__ gen,
                                               const float* __restrict__ inv,
                                               unsigned char* __restrict__ K) {
    __shared__ _Float16 As[128 * BK];   // 32 KB
    __shared__ _Float16 Bs[128 * BK];   // 32 KB
    int bid = blockIdx.x;          // 2048 = 8 problems * 16 * 16 tiles
    int p   = bid >> 8;
    int t   = bid & 255;
    int ti  = t >> 4, tj = t & 15;
    int ot  = p >> 2, b = p & 3;
    const float* X    = (ot == 0) ? src : tgt;
    const float* Y    = (ot == 0) ? tgt : gen;
    const float* invx = inv + (ot == 0 ? 0 : NTOT);
    const float* invy = inv + (ot == 0 ? NTOT : 2 * NTOT);
    int rowA0 = b * NP + ti * 128;
    int rowB0 = b * NP + tj * 128;

    int tid  = threadIdx.x;
    int w    = tid >> 6, lane = tid & 63;
    int wr   = w >> 1,  wc   = w & 1;
    int lr   = lane & 15, lk = lane >> 4;

    f32x4 acc[4][4];
    #pragma unroll
    for (int m = 0; m < 4; ++m)
        #pragma unroll
        for (int n = 0; n < 4; ++n) acc[m][n] = (f32x4){0.f, 0.f, 0.f, 0.f};

    for (int kb = 0; kb < DF; kb += BK) {
        __syncthreads();
        #pragma unroll
        for (int s = 0; s < 8; ++s) {
            int idx = tid + s * 256;      // 0..2047
            int row = idx >> 4;
            int g   = idx & 15;
            int gs  = g ^ (row & 7);
            const float4* xp = reinterpret_cast<const float4*>(
                X + (size_t)(rowA0 + row) * DF + kb + g * 8);
            float4 x0 = xp[0], x1 = xp[1];
            float  sa = invx[rowA0 + row];
            f16x8 hv;
            hv[0] = (_Float16)(x0.x * sa); hv[1] = (_Float16)(x0.y * sa);
            hv[2] = (_Float16)(x0.z * sa); hv[3] = (_Float16)(x0.w * sa);
            hv[4] = (_Float16)(x1.x * sa); hv[5] = (_Float16)(x1.y * sa);
            hv[6] = (_Float16)(x1.z * sa); hv[7] = (_Float16)(x1.w * sa);
            *reinterpret_cast<f16x8*>(&As[row * BK + gs * 8]) = hv;
            const float4* yp = reinterpret_cast<const float4*>(
                Y + (size_t)(rowB0 + row) * DF + kb + g * 8);
            float4 y0 = yp[0], y1 = yp[1];
            float  sb = invy[rowB0 + row];
            f16x8 hw;
            hw[0] = (_Float16)(y0.x * sb); hw[1] = (_Float16)(y0.y * sb);
            hw[2] = (_Float16)(y0.z * sb); hw[3] = (_Float16)(y0.w * sb);
            hw[4] = (_Float16)(y1.x * sb); hw[5] = (_Float16)(y1.y * sb);
            hw[6] = (_Float16)(y1.z * sb); hw[7] = (_Float16)(y1.w * sb);
            *reinterpret_cast<f16x8*>(&Bs[row * BK + gs * 8]) = hw;
        }
        __syncthreads();
        #pragma unroll
        for (int ks = 0; ks < BK / 32; ++ks) {
            int kg = ks * 4 + lk;
            f16x8 af[4], bf[4];
            #pragma unroll
            for (int m = 0; m < 4; ++m) {
                int row = wr * 64 + m * 16 + lr;
                af[m] = *reinterpret_cast<const f16x8*>(&As[row * BK + (kg ^ (row & 7)) * 8]);
            }
            #pragma unroll
            for (int n = 0; n < 4; ++n) {
                int row = wc * 64 + n * 16 + lr;
                bf[n] = *reinterpret_cast<const f16x8*>(&Bs[row * BK + (kg ^ (row & 7)) * 8]);
            }
            #pragma unroll
            for (int m = 0; m < 4; ++m)
                #pragma unroll
                for (int n = 0; n < 4; ++n)
                    acc[m][n] = __builtin_amdgcn_mfma_f32_16x16x32_f16(af[m], bf[n], acc[m][n], 0, 0, 0);
        }
    }

    unsigned char* Kp = K + (size_t)p * NP * NP;
    #pragma unroll
    for (int m = 0; m < 4; ++m) {
        #pragma unroll
        for (int r4 = 0; r4 < 4; ++r4) {
            int gi = ti * 128 + wr * 64 + m * 16 + lk * 4 + r4;
            #pragma unroll
            for (int n = 0; n < 4; ++n) {
                int gj = tj * 128 + wc * 64 + n * 16 + lr;
                float kv = __expf(acc[m][n][r4] - 1.0f);
                Kp[(size_t)gi * NP + gj] =
                    (unsigned char)__float2uint_rn(fminf(kv * SQ, 255.0f));
            }
        }
    }
}

// ---------------------------------------------------------------- persistent Sinkhorn
// 256 blocks (4 pairs * 64 slots). Block holds rows r0..r0+31 of problems g
// and g+4 as u8 in 128 KB dynamic LDS for ALL 50 iterations. Per-pair
// sense-reversing barrier on device-scope atomics. Final L1-diff fused.
__global__ __launch_bounds__(512) void k_persist(const unsigned char* __restrict__ Kq,
                                                 float* __restrict__ va,
                                                 float* __restrict__ sum,
                                                 unsigned int* __restrict__ cnt) {
    extern __shared__ unsigned char Ksh[];   // 64 * 2048 = 128 KB
    __shared__ float u_lds[64];
    __shared__ float red[8];

    const int bid  = blockIdx.x;     // 256
    const int g    = bid >> 6;       // pair 0..3
    const int slot = bid & 63;
    const int p1 = g, p2 = g + 4;
    const int r0 = slot * 32;        // rows of both problems; also v-zero col slice
    const int tid = threadIdx.x;
    const int w = tid >> 6, lane = tid & 63;

    // ---- load both 32-row tiles into LDS (rows of p1 -> 0..31, p2 -> 32..63)
    {
        const uint4* g1 = reinterpret_cast<const uint4*>(Kq + (size_t)p1 * NP * NP + (size_t)r0 * NP);
        const uint4* g2 = reinterpret_cast<const uint4*>(Kq + (size_t)p2 * NP * NP + (size_t)r0 * NP);
        uint4* s4 = reinterpret_cast<uint4*>(Ksh);
        #pragma unroll
        for (int i = 0; i < 8; ++i) {
            int idx = tid + i * 512;         // 0..4095 uint4s per tile
            s4[idx]        = g1[idx];
            s4[4096 + idx] = g2[idx];
        }
    }

    const int prob   = (w < 4) ? p1 : p2;    // this wave's problem
    const int rowoff = (w < 4) ? 0 : 32;     // LDS row offset of that problem
    const int rbase  = rowoff + (w & 3) * 8; // phase-1: 8 rows per wave
    const int cw     = (w & 3) * 512;        // phase-2: exclusive 512-col slab

    __syncthreads();

    for (int t = 0; t < NITER; ++t) {
        const float* vR = va + (size_t)((t + 2) % 3) * (NPROB * NP);
        float*       vW = va + (size_t)(t % 3)       * (NPROB * NP);
        float*       vZ = va + (size_t)((t + 1) % 3) * (NPROB * NP);

        // ---- v for this lane's interleaved col chunks [lane*16,+16) u [1024+lane*16,+16)
        float vr[32];
        if (t == 0) {
            #pragma unroll
            for (int c = 0; c < 32; ++c) vr[c] = 1.0f;
        } else {
            const float* vp = vR + (size_t)prob * NP;
            #pragma unroll
            for (int k = 0; k < 16; ++k) {
                float x = __hip_atomic_load(&vp[lane * 16 + k],
                                            __ATOMIC_RELAXED, __HIP_MEMORY_SCOPE_AGENT);
                float y = __hip_atomic_load(&vp[1024 + lane * 16 + k],
                                            __ATOMIC_RELAXED, __HIP_MEMORY_SCOPE_AGENT);
                vr[k]      = __fdividef(F_MU, x + EPS_V);
                vr[16 + k] = __fdividef(F_MU, y + EPS_V);
            }
        }

        // ---- phase 1: u for this wave's 8 rows (dot over LDS, shfl-reduce)
        #pragma unroll
        for (int r = 0; r < 8; ++r) {
            int row = rbase + r;
            const uint4* kr = reinterpret_cast<const uint4*>(Ksh + (size_t)row * NP);
            uint4 qa = kr[lane];        // bytes [lane*16, +16)
            uint4 qb = kr[64 + lane];   // bytes [1024 + lane*16, +16)
            float d = mac4(qa.x, vr)      + mac4(qa.y, vr + 4)
                    + mac4(qa.z, vr + 8)  + mac4(qa.w, vr + 12)
                    + mac4(qb.x, vr + 16) + mac4(qb.y, vr + 20)
                    + mac4(qb.z, vr + 24) + mac4(qb.w, vr + 28);
            #pragma unroll
            for (int off = 32; off; off >>= 1) d += __shfl_xor(d, off);
            if (lane == 0) u_lds[row] = __fdividef(F_MU, d + EPS_U);
        }
        __syncthreads();

        // ---- phase 2: K^T u partials over exclusive col slab (32 rows)
        float vacc[8] = {0.f, 0.f, 0.f, 0.f, 0.f, 0.f, 0.f, 0.f};
        const unsigned char* kbase = Ksh + (size_t)rowoff * NP + cw + lane * 8;
        #pragma unroll 8
        for (int r = 0; r < 32; ++r) {
            float ur = u_lds[rowoff + r];
            uint2 q = *reinterpret_cast<const uint2*>(kbase + (size_t)r * NP);
            vacc[0] += (float)(q.x & 255u)         * ur;
            vacc[1] += (float)((q.x >> 8)  & 255u) * ur;
            vacc[2] += (float)((q.x >> 16) & 255u) * ur;
            vacc[3] += (float)(q.x >> 24)          * ur;
            vacc[4] += (float)(q.y & 255u)         * ur;
            vacc[5] += (float)((q.y >> 8)  & 255u) * ur;
            vacc[6] += (float)((q.y >> 16) & 255u) * ur;
            vacc[7] += (float)(q.y >> 24)          * ur;
        }
        {
            float* vWp = vW + (size_t)prob * NP + cw + lane * 8;
            #pragma unroll
            for (int k2 = 0; k2 < 8; ++k2) atomicAdd(&vWp[k2], vacc[k2]);
        }

        // ---- zero next buffer's slice (device-visible)
        if (tid < 64) {
            int pr = (tid < 32) ? p1 : p2;
            atomicExch(&vZ[(size_t)pr * NP + r0 + (tid & 31)], 0.0f);
        }

        // ---- per-pair barrier (64 blocks)
        __syncthreads();   // drains each wave's vmcnt (atomics complete)
        if (tid == 0) {
            __hip_atomic_fetch_add(&cnt[g], 1u, __ATOMIC_RELEASE, __HIP_MEMORY_SCOPE_AGENT);
            unsigned int target = 64u * (unsigned int)(t + 1);
            while (__hip_atomic_load(&cnt[g], __ATOMIC_ACQUIRE, __HIP_MEMORY_SCOPE_AGENT) < target)
                __builtin_amdgcn_s_sleep(4);
        }
        __syncthreads();
    }

    // ---- fused final reduce: mean-sum |u1 K1 v1 - u2 K2 v2| over own rows
    {
        const float* vF1 = va + (size_t)((NITER - 1) % 3) * (NPROB * NP) + (size_t)p1 * NP;
        const float* vF2 = va + (size_t)((NITER - 1) % 3) * (NPROB * NP) + (size_t)p2 * NP;
        float v1r[32], v2r[32];
        #pragma unroll
        for (int k = 0; k < 16; ++k) {
            float a = __hip_atomic_load(&vF1[lane * 16 + k],
                                        __ATOMIC_RELAXED, __HIP_MEMORY_SCOPE_AGENT);
            float b = __hip_atomic_load(&vF1[1024 + lane * 16 + k],
                                        __ATOMIC_RELAXED, __HIP_MEMORY_SCOPE_AGENT);
            float c = __hip_atomic_load(&vF2[lane * 16 + k],
                                        __ATOMIC_RELAXED, __HIP_MEMORY_SCOPE_AGENT);
            float e = __hip_atomic_load(&vF2[1024 + lane * 16 + k],
                                        __ATOMIC_RELAXED, __HIP_MEMORY_SCOPE_AGENT);
            v1r[k]      = __fdividef(F_MU, a + EPS_V);
            v1r[16 + k] = __fdividef(F_MU, b + EPS_V);
            v2r[k]      = __fdividef(F_MU, c + EPS_V);
            v2r[16 + k] = __fdividef(F_MU, e + EPS_V);
        }
        float acc = 0.f;
        #pragma unroll
        for (int r = 0; r < 4; ++r) {
            int row = w * 4 + r;            // 8 waves x 4 = rows 0..31
            float u1 = u_lds[row], u2 = u_lds[32 + row];
            const uint4* k1 = reinterpret_cast<const uint4*>(Ksh + (size_t)row * NP);
            const uint4* k2 = reinterpret_cast<const uint4*>(Ksh + (size_t)(32 + row) * NP);
            uint4 a1 = k1[lane], b1 = k1[64 + lane];
            uint4 a2 = k2[lane], b2 = k2[64 + lane];
            acc += ad4(a1.x, a2.x, u1, u2, v1r + 0,  v2r + 0);
            acc += ad4(a1.y, a2.y, u1, u2, v1r + 4,  v2r + 4);
            acc += ad4(a1.z, a2.z, u1, u2, v1r + 8,  v2r + 8);
            acc += ad4(a1.w, a2.w, u1, u2, v1r + 12, v2r + 12);
            acc += ad4(b1.x, b2.x, u1, u2, v1r + 16, v2r + 16);
            acc += ad4(b1.y, b2.y, u1, u2, v1r + 20, v2r + 20);
            acc += ad4(b1.z, b2.z, u1, u2, v1r + 24, v2r + 24);
            acc += ad4(b1.w, b2.w, u1, u2, v1r + 28, v2r + 28);
        }
        #pragma unroll
        for (int off = 32; off; off >>= 1) acc += __shfl_xor(acc, off);
        if (lane == 0) red[w] = acc;
        __syncthreads();
        if (tid == 0)
            atomicAdd(sum, red[0] + red[1] + red[2] + red[3]
                         + red[4] + red[5] + red[6] + red[7]);
    }
}

__global__ void k_final(const float* __restrict__ sum, float* __restrict__ out) {
    out[0] = sum[0] * (1.0f / 16777216.0f);   // / (4*2048*2048)
}

// ---------------------------------------------------------------- launch
extern "C" void kernel_launch(void* const* d_in, const int* in_sizes, int n_in,
                              void* d_out, int out_size, void* d_ws, size_t ws_size,
                              hipStream_t stream) {
    const float* src = (const float*)d_in[0];
    const float* tgt = (const float*)d_in[1];
    const float* gen = (const float*)d_in[2];
    float* ws  = (float*)d_ws;
    unsigned char* Kq = (unsigned char*)(ws + OFF_K);
    float* va  = ws + OFF_VA;
    float* inv = ws + OFF_INV;
    float* sum = ws + OFF_SUM;
    unsigned int* cnt = (unsigned int*)(ws + OFF_CNT);
    float* out = (float*)d_out;

    hipLaunchKernelGGL(k_norms, dim3(6144), dim3(256), 0, stream, src, tgt, gen, inv);
    hipLaunchKernelGGL(k_init,  dim3(65),   dim3(256), 0, stream, va, sum, cnt);
    hipLaunchKernelGGL(k_build, dim3(2048), dim3(256), 0, stream, src, tgt, gen, inv, Kq);

    {
        const unsigned char* Kq_ = Kq;
        float* va_ = va;
        float* sum_ = sum;
        unsigned int* cnt_ = cnt;
        void* args[4] = { (void*)&Kq_, (void*)&va_, (void*)&sum_, (void*)&cnt_ };
        hipLaunchCooperativeKernel((const void*)k_persist, dim3(256), dim3(512),
                                   args, 131072u, stream);
    }

    hipLaunchKernelGGL(k_final, dim3(1), dim3(1), 0, stream, sum, out);
}

// Round 7
// 2807.090 us; speedup vs baseline: 1.8078x; 1.0276x over previous
//
#include <hip/hip_runtime.h>
#include <math.h>

#define NP 2048           // points per batch (n == m)
#define DF 256            // feature dim
#define NPROB 8           // 2 OTs * 4 batches
#define NTOT 8192         // total rows per feature tensor
#define NITER 50

constexpr float F_MU  = 1.0f / 2048.0f;   // uniform marginal 1/n
constexpr float SQ    = 255.0f;           // K u8 quantization scale
constexpr float EPS_U = 255.0f * 1e-8f;   // stab for u-update (scale-consistent)
constexpr float EPS_V = 1e-8f;            // stab for v-update (unscaled)

typedef _Float16 f16x8 __attribute__((ext_vector_type(8)));
typedef float    f32x4 __attribute__((ext_vector_type(4)));

// workspace layout (float units)
constexpr size_t OFF_K     = 0;                            // u8[8*2048*2048] = 33.5 MB
constexpr size_t SZ_Kf     = (size_t)NPROB * NP * NP / 4;  // 8,388,608 floats
constexpr size_t OFF_VPART = OFF_K + SZ_Kf;                // [prob][slot][2048] partials
constexpr size_t SZ_VPART  = (size_t)NPROB * 64 * NP;      // 1,048,576 floats (4 MB)
constexpr size_t OFF_VFULL = OFF_VPART + SZ_VPART;         // [prob][2048] raw col sums
constexpr size_t SZ_VFULL  = (size_t)NPROB * NP;           // 16,384
constexpr size_t OFF_INV   = OFF_VFULL + SZ_VFULL;
constexpr size_t SZ_INV    = (size_t)3 * NTOT;
constexpr size_t OFF_SUM   = OFF_INV + SZ_INV;
constexpr size_t OFF_CNT   = OFF_SUM + 1;                  // 8 uint barrier counters

__device__ inline float mac4(unsigned a, const float* v) {
    return (float)(a & 255u)         * v[0] + (float)((a >> 8) & 255u) * v[1]
         + (float)((a >> 16) & 255u) * v[2] + (float)(a >> 24)         * v[3];
}

__device__ inline float ad4(unsigned a, unsigned b, float u1, float u2,
                            const float* v1, const float* v2) {
    float s;
    s  = fabsf(u1 * (float)(a & 255u)          * v1[0] - u2 * (float)(b & 255u)          * v2[0]);
    s += fabsf(u1 * (float)((a >> 8)  & 255u)  * v1[1] - u2 * (float)((b >> 8)  & 255u)  * v2[1]);
    s += fabsf(u1 * (float)((a >> 16) & 255u)  * v1[2] - u2 * (float)((b >> 16) & 255u)  * v2[2]);
    s += fabsf(u1 * (float)(a >> 24)           * v1[3] - u2 * (float)(b >> 24)           * v2[3]);
    return s;
}

// ---------------------------------------------------------------- row norms
__global__ __launch_bounds__(256) void k_norms(const float* __restrict__ src,
                                               const float* __restrict__ tgt,
                                               const float* __restrict__ gen,
                                               float* __restrict__ inv) {
    int gw   = (blockIdx.x * 256 + threadIdx.x) >> 6;   // 0 .. 3*8192-1
    int lane = threadIdx.x & 63;
    int a = gw >> 13;
    int r = gw & 8191;
    const float* base = (a == 0 ? src : (a == 1 ? tgt : gen)) + (size_t)r * DF;
    float4 x = reinterpret_cast<const float4*>(base)[lane];
    float s = x.x * x.x + x.y * x.y + x.z * x.z + x.w * x.w;
    #pragma unroll
    for (int off = 32; off; off >>= 1) s += __shfl_xor(s, off);
    if (lane == 0) inv[gw] = 1.0f / (sqrtf(s) + 1e-8f);
}

// ---------------------------------------------------------------- init (sum + barrier counters)
__global__ void k_init(float* __restrict__ sum, unsigned int* __restrict__ cnt) {
    int i = threadIdx.x;
    if (i == 0) sum[0] = 0.0f;
    if (i < 8) cnt[i] = 0u;
}

// ---------------------------------------------------------------- K build via f16 MFMA
// 128x128 tile per block, 4 waves in 2x2, each wave 64x64 via 4x4 fragments of
// mfma_f32_16x16x32_f16. BK=128 K-panel staged in LDS (f16, XOR granule
// swizzle). Epilogue: exp + u8 quantize (scale 255).
#define BK 128
__global__ __launch_bounds__(256) void k_build(const float* __restrict__ src,
                                               const float* __restrict__ tgt,
                                               const float* __restrict__ gen,
                                               const float* __restrict__ inv,
                                               unsigned char* __restrict__ K) {
    __shared__ _Float16 As[128 * BK];   // 32 KB
    __shared__ _Float16 Bs[128 * BK];   // 32 KB
    int bid = blockIdx.x;          // 2048 = 8 problems * 16 * 16 tiles
    int p   = bid >> 8;
    int t   = bid & 255;
    int ti  = t >> 4, tj = t & 15;
    int ot  = p >> 2, b = p & 3;
    const float* X    = (ot == 0) ? src : tgt;
    const float* Y    = (ot == 0) ? tgt : gen;
    const float* invx = inv + (ot == 0 ? 0 : NTOT);
    const float* invy = inv + (ot == 0 ? NTOT : 2 * NTOT);
    int rowA0 = b * NP + ti * 128;
    int rowB0 = b * NP + tj * 128;

    int tid  = threadIdx.x;
    int w    = tid >> 6, lane = tid & 63;
    int wr   = w >> 1,  wc   = w & 1;
    int lr   = lane & 15, lk = lane >> 4;

    f32x4 acc[4][4];
    #pragma unroll
    for (int m = 0; m < 4; ++m)
        #pragma unroll
        for (int n = 0; n < 4; ++n) acc[m][n] = (f32x4){0.f, 0.f, 0.f, 0.f};

    for (int kb = 0; kb < DF; kb += BK) {
        __syncthreads();
        #pragma unroll
        for (int s = 0; s < 8; ++s) {
            int idx = tid + s * 256;      // 0..2047
            int row = idx >> 4;
            int g   = idx & 15;
            int gs  = g ^ (row & 7);
            const float4* xp = reinterpret_cast<const float4*>(
                X + (size_t)(rowA0 + row) * DF + kb + g * 8);
            float4 x0 = xp[0], x1 = xp[1];
            float  sa = invx[rowA0 + row];
            f16x8 hv;
            hv[0] = (_Float16)(x0.x * sa); hv[1] = (_Float16)(x0.y * sa);
            hv[2] = (_Float16)(x0.z * sa); hv[3] = (_Float16)(x0.w * sa);
            hv[4] = (_Float16)(x1.x * sa); hv[5] = (_Float16)(x1.y * sa);
            hv[6] = (_Float16)(x1.z * sa); hv[7] = (_Float16)(x1.w * sa);
            *reinterpret_cast<f16x8*>(&As[row * BK + gs * 8]) = hv;
            const float4* yp = reinterpret_cast<const float4*>(
                Y + (size_t)(rowB0 + row) * DF + kb + g * 8);
            float4 y0 = yp[0], y1 = yp[1];
            float  sb = invy[rowB0 + row];
            f16x8 hw;
            hw[0] = (_Float16)(y0.x * sb); hw[1] = (_Float16)(y0.y * sb);
            hw[2] = (_Float16)(y0.z * sb); hw[3] = (_Float16)(y0.w * sb);
            hw[4] = (_Float16)(y1.x * sb); hw[5] = (_Float16)(y1.y * sb);
            hw[6] = (_Float16)(y1.z * sb); hw[7] = (_Float16)(y1.w * sb);
            *reinterpret_cast<f16x8*>(&Bs[row * BK + gs * 8]) = hw;
        }
        __syncthreads();
        #pragma unroll
        for (int ks = 0; ks < BK / 32; ++ks) {
            int kg = ks * 4 + lk;
            f16x8 af[4], bf[4];
            #pragma unroll
            for (int m = 0; m < 4; ++m) {
                int row = wr * 64 + m * 16 + lr;
                af[m] = *reinterpret_cast<const f16x8*>(&As[row * BK + (kg ^ (row & 7)) * 8]);
            }
            #pragma unroll
            for (int n = 0; n < 4; ++n) {
                int row = wc * 64 + n * 16 + lr;
                bf[n] = *reinterpret_cast<const f16x8*>(&Bs[row * BK + (kg ^ (row & 7)) * 8]);
            }
            #pragma unroll
            for (int m = 0; m < 4; ++m)
                #pragma unroll
                for (int n = 0; n < 4; ++n)
                    acc[m][n] = __builtin_amdgcn_mfma_f32_16x16x32_f16(af[m], bf[n], acc[m][n], 0, 0, 0);
        }
    }

    unsigned char* Kp = K + (size_t)p * NP * NP;
    #pragma unroll
    for (int m = 0; m < 4; ++m) {
        #pragma unroll
        for (int r4 = 0; r4 < 4; ++r4) {
            int gi = ti * 128 + wr * 64 + m * 16 + lk * 4 + r4;
            #pragma unroll
            for (int n = 0; n < 4; ++n) {
                int gj = tj * 128 + wc * 64 + n * 16 + lr;
                float kv = __expf(acc[m][n][r4] - 1.0f);
                Kp[(size_t)gi * NP + gj] =
                    (unsigned char)__float2uint_rn(fminf(kv * SQ, 255.0f));
            }
        }
    }
}

// ---------------------------------------------------------------- persistent Sinkhorn
// 256 blocks (4 pairs * 64 slots). Block holds rows r0..r0+31 of problems g
// and g+4 as u8 in 128 KB dynamic LDS for ALL 50 iterations.
// Per iter: u (block-local) -> partial K^T u (coalesced plain stores to vpart)
// -> barrier A -> distributed reduce of own 32-col slab -> vfull -> barrier B.
// Explicit __threadfence() (device-scope) before each barrier increment makes
// the plain data stores visible across XCDs regardless of fence codegen.
__global__ __launch_bounds__(512) void k_persist(const unsigned char* __restrict__ Kq,
                                                 float* __restrict__ vpart,
                                                 float* __restrict__ vfull,
                                                 float* __restrict__ sum,
                                                 unsigned int* __restrict__ cnt) {
    extern __shared__ unsigned char Ksh[];   // 64 * 2048 = 128 KB
    __shared__ float u_lds[64];
    __shared__ float rpart[2][8][32];
    __shared__ float red[8];

    const int bid  = blockIdx.x;     // 256
    const int g    = bid >> 6;       // pair 0..3
    const int slot = bid & 63;
    const int p1 = g, p2 = g + 4;
    const int r0 = slot * 32;        // global row base of this block's stripes
    const int tid = threadIdx.x;
    const int w = tid >> 6, lane = tid & 63;

    // ---- load both 32-row tiles into LDS (rows of p1 -> 0..31, p2 -> 32..63)
    {
        const uint4* g1 = reinterpret_cast<const uint4*>(Kq + (size_t)p1 * NP * NP + (size_t)r0 * NP);
        const uint4* g2 = reinterpret_cast<const uint4*>(Kq + (size_t)p2 * NP * NP + (size_t)r0 * NP);
        uint4* s4 = reinterpret_cast<uint4*>(Ksh);
        #pragma unroll
        for (int i = 0; i < 8; ++i) {
            int idx = tid + i * 512;         // 0..4095 uint4s per tile
            s4[idx]        = g1[idx];
            s4[4096 + idx] = g2[idx];
        }
    }

    const int prob   = (w < 4) ? p1 : p2;    // this wave's problem
    const int rowoff = (w < 4) ? 0 : 32;     // LDS row offset of that problem
    const int rbase  = rowoff + (w & 3) * 8; // phase-1: 8 rows per wave
    const int cw     = (w & 3) * 512;        // phase-2: exclusive 512-col slab

    __syncthreads();

    for (int t = 0; t < NITER; ++t) {
        // ---- v for this lane's cols [lane*16,+16) u [1024+lane*16,+16)
        float vr[32];
        if (t == 0) {
            #pragma unroll
            for (int c = 0; c < 32; ++c) vr[c] = 1.0f;
        } else {
            const float* vp = vfull + (size_t)prob * NP;
            #pragma unroll
            for (int j = 0; j < 4; ++j) {
                float4 x = *reinterpret_cast<const float4*>(&vp[lane * 16 + j * 4]);
                float4 y = *reinterpret_cast<const float4*>(&vp[1024 + lane * 16 + j * 4]);
                vr[j*4+0]    = __fdividef(F_MU, x.x + EPS_V);
                vr[j*4+1]    = __fdividef(F_MU, x.y + EPS_V);
                vr[j*4+2]    = __fdividef(F_MU, x.z + EPS_V);
                vr[j*4+3]    = __fdividef(F_MU, x.w + EPS_V);
                vr[16+j*4+0] = __fdividef(F_MU, y.x + EPS_V);
                vr[16+j*4+1] = __fdividef(F_MU, y.y + EPS_V);
                vr[16+j*4+2] = __fdividef(F_MU, y.z + EPS_V);
                vr[16+j*4+3] = __fdividef(F_MU, y.w + EPS_V);
            }
        }

        // ---- phase 1: u for this wave's 8 rows (dot over LDS, shfl-reduce)
        #pragma unroll
        for (int r = 0; r < 8; ++r) {
            int row = rbase + r;
            const uint4* kr = reinterpret_cast<const uint4*>(Ksh + (size_t)row * NP);
            uint4 qa = kr[lane];        // bytes [lane*16, +16)
            uint4 qb = kr[64 + lane];   // bytes [1024 + lane*16, +16)
            float d = mac4(qa.x, vr)      + mac4(qa.y, vr + 4)
                    + mac4(qa.z, vr + 8)  + mac4(qa.w, vr + 12)
                    + mac4(qb.x, vr + 16) + mac4(qb.y, vr + 20)
                    + mac4(qb.z, vr + 24) + mac4(qb.w, vr + 28);
            #pragma unroll
            for (int off = 32; off; off >>= 1) d += __shfl_xor(d, off);
            if (lane == 0) u_lds[row] = __fdividef(F_MU, d + EPS_U);
        }
        __syncthreads();

        // ---- phase 2: K^T u partials over exclusive col slab (32 rows)
        float vacc[8] = {0.f, 0.f, 0.f, 0.f, 0.f, 0.f, 0.f, 0.f};
        const unsigned char* kbase = Ksh + (size_t)rowoff * NP + cw + lane * 8;
        #pragma unroll 8
        for (int r = 0; r < 32; ++r) {
            float ur = u_lds[rowoff + r];
            uint2 q = *reinterpret_cast<const uint2*>(kbase + (size_t)r * NP);
            vacc[0] += (float)(q.x & 255u)         * ur;
            vacc[1] += (float)((q.x >> 8)  & 255u) * ur;
            vacc[2] += (float)((q.x >> 16) & 255u) * ur;
            vacc[3] += (float)(q.x >> 24)          * ur;
            vacc[4] += (float)(q.y & 255u)         * ur;
            vacc[5] += (float)((q.y >> 8)  & 255u) * ur;
            vacc[6] += (float)((q.y >> 16) & 255u) * ur;
            vacc[7] += (float)(q.y >> 24)          * ur;
        }
        {   // coalesced plain float4 stores of the partial slab
            float* vPp = vpart + ((size_t)prob * 64 + slot) * NP + cw + lane * 8;
            *reinterpret_cast<float4*>(vPp)     = make_float4(vacc[0], vacc[1], vacc[2], vacc[3]);
            *reinterpret_cast<float4*>(vPp + 4) = make_float4(vacc[4], vacc[5], vacc[6], vacc[7]);
        }

        // ---- barrier A (release partials, acquire all partials)
        __syncthreads();
        if (tid == 0) {
            __threadfence();   // device-scope: write back this XCD's L2 (vpart)
            __hip_atomic_fetch_add(&cnt[g], 1u, __ATOMIC_RELEASE, __HIP_MEMORY_SCOPE_AGENT);
            unsigned int target = 64u * (unsigned int)(t + 1);
            while (__hip_atomic_load(&cnt[g], __ATOMIC_ACQUIRE, __HIP_MEMORY_SCOPE_AGENT) < target)
                __builtin_amdgcn_s_sleep(2);
        }
        __syncthreads();

        // ---- distributed reduce: this block's 32-col slab, both problems
        {
            int half = tid >> 8;             // 0: p1, 1: p2
            int pr   = half ? p2 : p1;
            int idx  = tid & 255;
            int c    = idx & 31;
            int k    = idx >> 5;             // 0..7 slot-groups
            const float* vp = vpart + (size_t)pr * 64 * NP + (size_t)r0 + c;
            float s = 0.f;
            #pragma unroll
            for (int j = 0; j < 8; ++j)
                s += vp[(size_t)(k * 8 + j) * NP];
            rpart[half][k][c] = s;
        }
        __syncthreads();
        if (tid < 64) {
            int half = tid >> 5;
            int pr   = half ? p2 : p1;
            int c    = tid & 31;
            float s = 0.f;
            #pragma unroll
            for (int k = 0; k < 8; ++k) s += rpart[half][k][c];
            vfull[(size_t)pr * NP + r0 + c] = s;   // raw col sum (divide at load)
        }

        // ---- barrier B (release vfull, acquire before next u-phase)
        __syncthreads();
        if (tid == 0) {
            __threadfence();   // device-scope: write back vfull
            __hip_atomic_fetch_add(&cnt[4 + g], 1u, __ATOMIC_RELEASE, __HIP_MEMORY_SCOPE_AGENT);
            unsigned int target = 64u * (unsigned int)(t + 1);
            while (__hip_atomic_load(&cnt[4 + g], __ATOMIC_ACQUIRE, __HIP_MEMORY_SCOPE_AGENT) < target)
                __builtin_amdgcn_s_sleep(2);
        }
        __syncthreads();
    }

    // ---- fused final reduce: mean-sum |u1 K1 v1 - u2 K2 v2| over own rows
    {
        const float* vF1 = vfull + (size_t)p1 * NP;
        const float* vF2 = vfull + (size_t)p2 * NP;
        float v1r[32], v2r[32];
        #pragma unroll
        for (int j = 0; j < 4; ++j) {
            float4 a = *reinterpret_cast<const float4*>(&vF1[lane * 16 + j * 4]);
            float4 b = *reinterpret_cast<const float4*>(&vF1[1024 + lane * 16 + j * 4]);
            float4 c = *reinterpret_cast<const float4*>(&vF2[lane * 16 + j * 4]);
            float4 e = *reinterpret_cast<const float4*>(&vF2[1024 + lane * 16 + j * 4]);
            v1r[j*4+0] = __fdividef(F_MU, a.x + EPS_V); v1r[j*4+1] = __fdividef(F_MU, a.y + EPS_V);
            v1r[j*4+2] = __fdividef(F_MU, a.z + EPS_V); v1r[j*4+3] = __fdividef(F_MU, a.w + EPS_V);
            v1r[16+j*4+0] = __fdividef(F_MU, b.x + EPS_V); v1r[16+j*4+1] = __fdividef(F_MU, b.y + EPS_V);
            v1r[16+j*4+2] = __fdividef(F_MU, b.z + EPS_V); v1r[16+j*4+3] = __fdividef(F_MU, b.w + EPS_V);
            v2r[j*4+0] = __fdividef(F_MU, c.x + EPS_V); v2r[j*4+1] = __fdividef(F_MU, c.y + EPS_V);
            v2r[j*4+2] = __fdividef(F_MU, c.z + EPS_V); v2r[j*4+3] = __fdividef(F_MU, c.w + EPS_V);
            v2r[16+j*4+0] = __fdividef(F_MU, e.x + EPS_V); v2r[16+j*4+1] = __fdividef(F_MU, e.y + EPS_V);
            v2r[16+j*4+2] = __fdividef(F_MU, e.z + EPS_V); v2r[16+j*4+3] = __fdividef(F_MU, e.w + EPS_V);
        }
        float acc = 0.f;
        #pragma unroll
        for (int r = 0; r < 4; ++r) {
            int row = w * 4 + r;            // 8 waves x 4 = rows 0..31
            float u1 = u_lds[row], u2 = u_lds[32 + row];
            const uint4* k1 = reinterpret_cast<const uint4*>(Ksh + (size_t)row * NP);
            const uint4* k2 = reinterpret_cast<const uint4*>(Ksh + (size_t)(32 + row) * NP);
            uint4 a1 = k1[lane], b1 = k1[64 + lane];
            uint4 a2 = k2[lane], b2 = k2[64 + lane];
            acc += ad4(a1.x, a2.x, u1, u2, v1r + 0,  v2r + 0);
            acc += ad4(a1.y, a2.y, u1, u2, v1r + 4,  v2r + 4);
            acc += ad4(a1.z, a2.z, u1, u2, v1r + 8,  v2r + 8);
            acc += ad4(a1.w, a2.w, u1, u2, v1r + 12, v2r + 12);
            acc += ad4(b1.x, b2.x, u1, u2, v1r + 16, v2r + 16);
            acc += ad4(b1.y, b2.y, u1, u2, v1r + 20, v2r + 20);
            acc += ad4(b1.z, b2.z, u1, u2, v1r + 24, v2r + 24);
            acc += ad4(b1.w, b2.w, u1, u2, v1r + 28, v2r + 28);
        }
        #pragma unroll
        for (int off = 32; off; off >>= 1) acc += __shfl_xor(acc, off);
        if (lane == 0) red[w] = acc;
        __syncthreads();
        if (tid == 0)
            atomicAdd(sum, red[0] + red[1] + red[2] + red[3]
                         + red[4] + red[5] + red[6] + red[7]);
    }
}

__global__ void k_final(const float* __restrict__ sum, float* __restrict__ out) {
    out[0] = sum[0] * (1.0f / 16777216.0f);   // / (4*2048*2048)
}

// ---------------------------------------------------------------- launch
extern "C" void kernel_launch(void* const* d_in, const int* in_sizes, int n_in,
                              void* d_out, int out_size, void* d_ws, size_t ws_size,
                              hipStream_t stream) {
    const float* src = (const float*)d_in[0];
    const float* tgt = (const float*)d_in[1];
    const float* gen = (const float*)d_in[2];
    float* ws  = (float*)d_ws;
    unsigned char* Kq = (unsigned char*)(ws + OFF_K);
    float* vpart = ws + OFF_VPART;
    float* vfull = ws + OFF_VFULL;
    float* inv   = ws + OFF_INV;
    float* sum   = ws + OFF_SUM;
    unsigned int* cnt = (unsigned int*)(ws + OFF_CNT);
    float* out = (float*)d_out;

    hipLaunchKernelGGL(k_norms, dim3(6144), dim3(256), 0, stream, src, tgt, gen, inv);
    hipLaunchKernelGGL(k_init,  dim3(1),    dim3(64),  0, stream, sum, cnt);
    hipLaunchKernelGGL(k_build, dim3(2048), dim3(256), 0, stream, src, tgt, gen, inv, Kq);

    {
        const unsigned char* Kq_ = Kq;
        float* vpart_ = vpart;
        float* vfull_ = vfull;
        float* sum_ = sum;
        unsigned int* cnt_ = cnt;
        void* args[5] = { (void*)&Kq_, (void*)&vpart_, (void*)&vfull_,
                          (void*)&sum_, (void*)&cnt_ };
        hipLaunchCooperativeKernel((const void*)k_persist, dim3(256), dim3(512),
                                   args, 131072u, stream);
    }

    hipLaunchKernelGGL(k_final, dim3(1), dim3(1), 0, stream, sum, out);
}